// Round 1
// baseline (124.139 us; speedup 1.0000x reference)
//
#include <hip/hip_runtime.h>

// Problem constants (from reference): B=2, N=24, E=128, H=8, D=16
#define BB 2
#define NN 24
#define EE 128
#define HH 8
#define DD 16
#define ROWS (BB * NN * NN)   // 1152 rows of length E

// ---------------------------------------------------------------------------
// K1: fused projections.
// Row r = ((b*N + i)*N + j).  lk[r] = query[r] @ W_lk.T ; rk[r] = key_t[r] @ W_rk.T ;
// lv[r] = value[r] @ W_lv.T ; rv[r] = value[r] @ W_rv.T.
// One block per row, 256 threads -> 512 length-128 dot products (2 per thread).
// ---------------------------------------------------------------------------
__global__ __launch_bounds__(256) void proj_kernel(
    const float* __restrict__ query,
    const float* __restrict__ key_t,
    const float* __restrict__ value,
    const float* __restrict__ W_lk,
    const float* __restrict__ W_rk,
    const float* __restrict__ W_lv,
    const float* __restrict__ W_rv,
    float* __restrict__ lk,
    float* __restrict__ rk,
    float* __restrict__ lv,
    float* __restrict__ rv)
{
    __shared__ float qS[EE];
    __shared__ float kS[EE];
    __shared__ float vS[EE];

    const int r   = blockIdx.x;
    const int tid = threadIdx.x;

    if (tid < EE) {
        qS[tid] = query[r * EE + tid];
        kS[tid] = key_t[r * EE + tid];
        vS[tid] = value[r * EE + tid];
    }
    __syncthreads();

    // idx in [0,512): mat = idx>>7 (0..3), j = idx&127
    for (int idx = tid; idx < 4 * EE; idx += 256) {
        const int mat = idx >> 7;
        const int j   = idx & (EE - 1);
        const float* W;
        const float* xs;
        float* o;
        switch (mat) {
            case 0:  W = W_lk; xs = qS; o = lk; break;
            case 1:  W = W_rk; xs = kS; o = rk; break;
            case 2:  W = W_lv; xs = vS; o = lv; break;
            default: W = W_rv; xs = vS; o = rv; break;
        }
        const float4* w4 = (const float4*)(W + j * EE);
        const float4* x4 = (const float4*)xs;
        float acc = 0.f;
        #pragma unroll
        for (int i = 0; i < EE / 4; ++i) {
            float4 a = w4[i];
            float4 b = x4[i];
            acc += a.x * b.x + a.y * b.y + a.z * b.z + a.w * b.w;
        }
        o[r * EE + j] = acc;
    }
}

// ---------------------------------------------------------------------------
// K2: attention core + fused output projection.
// One block per (b, x, y).  Stages lk[b,x,:,:], rk[b,:,y,:], lv[b,x,:,:],
// rv[b,:,y,:] (each 24x128 fp32) in LDS, computes
//   scores[a,h] = (1/4) * sum_d lk[a,h,d]*rk[a,h,d]
//   att = softmax_a(scores)
//   xloc[h*16+d] = sum_a att[a,h] * lv[a,h*16+d] * rv[a,h*16+d]
//   out[b,x,y,j] = sum_i xloc[i] * W_out[j,i]
// ---------------------------------------------------------------------------
__global__ __launch_bounds__(256) void attn_kernel(
    const float* __restrict__ lk,
    const float* __restrict__ rk,
    const float* __restrict__ lv,
    const float* __restrict__ rv,
    const float* __restrict__ W_out,
    float* __restrict__ out)
{
    __shared__ float lkS[NN][EE];
    __shared__ float rkS[NN][EE];
    __shared__ float lvS[NN][EE];
    __shared__ float rvS[NN][EE];
    __shared__ float sS[NN][HH];
    __shared__ float attS[NN][HH];
    __shared__ float xloc[EE];

    const int tid = threadIdx.x;
    const int blk = blockIdx.x;              // ((b*N + x)*N + y)
    const int y   = blk % NN;
    const int x   = (blk / NN) % NN;
    const int b   = blk / (NN * NN);

    // lk/lv slices are contiguous (a is the inner row index): 3072 floats each
    const float4* lk4 = (const float4*)(lk + (size_t)((b * NN + x) * NN) * EE);
    const float4* lv4 = (const float4*)(lv + (size_t)((b * NN + x) * NN) * EE);
    for (int i = tid; i < NN * EE / 4; i += 256) {
        ((float4*)lkS)[i] = lk4[i];
        ((float4*)lvS)[i] = lv4[i];
    }
    // rk/rv slices: stride N*E between consecutive a
    for (int i = tid; i < NN * EE / 4; i += 256) {
        const int a = i >> 5;       // /32 float4 per row
        const int c = i & 31;
        const float4* r4 = (const float4*)(rk + (size_t)((b * NN + a) * NN + y) * EE);
        const float4* v4 = (const float4*)(rv + (size_t)((b * NN + a) * NN + y) * EE);
        ((float4*)rkS[a])[c] = r4[c];
        ((float4*)rvS[a])[c] = v4[c];
    }
    __syncthreads();

    // scores: 24*8 = 192 dots of length 16
    if (tid < NN * HH) {
        const int a = tid / HH;
        const int h = tid % HH;
        float acc = 0.f;
        #pragma unroll
        for (int d = 0; d < DD; ++d)
            acc += lkS[a][h * DD + d] * rkS[a][h * DD + d];
        sS[a][h] = acc * 0.25f;   // 1/sqrt(16)
    }
    __syncthreads();

    // softmax over a, per head (8 serial threads; only 24 elements each)
    if (tid < HH) {
        const int h = tid;
        float m = -1e30f;
        #pragma unroll
        for (int a = 0; a < NN; ++a) m = fmaxf(m, sS[a][h]);
        float s = 0.f;
        float e[NN];
        #pragma unroll
        for (int a = 0; a < NN; ++a) { e[a] = __expf(sS[a][h] - m); s += e[a]; }
        const float inv = 1.f / s;
        #pragma unroll
        for (int a = 0; a < NN; ++a) attS[a][h] = e[a] * inv;
    }
    __syncthreads();

    // weighted outer-product reduction over a
    if (tid < EE) {
        const int h = tid / DD;
        float acc = 0.f;
        #pragma unroll
        for (int a = 0; a < NN; ++a)
            acc += attS[a][h] * lvS[a][tid] * rvS[a][tid];
        xloc[tid] = acc;
    }
    __syncthreads();

    // fused output projection: 128 dots of length 128, split 2 ways per dot
    {
        const int j    = tid >> 1;
        const int half = tid & 1;
        const float4* w4 = (const float4*)(W_out + j * EE + half * 64);
        const float4* x4 = (const float4*)(xloc + half * 64);
        float acc = 0.f;
        #pragma unroll
        for (int i = 0; i < 16; ++i) {
            float4 a = w4[i];
            float4 b = x4[i];
            acc += a.x * b.x + a.y * b.y + a.z * b.z + a.w * b.w;
        }
        acc += __shfl_xor(acc, 1);
        if (half == 0) out[(size_t)blk * EE + j] = acc;
    }
}

extern "C" void kernel_launch(void* const* d_in, const int* in_sizes, int n_in,
                              void* d_out, int out_size, void* d_ws, size_t ws_size,
                              hipStream_t stream) {
    const float* query = (const float*)d_in[0];
    const float* key_t = (const float*)d_in[1];
    const float* value = (const float*)d_in[2];
    const float* W_lk  = (const float*)d_in[3];
    const float* W_rk  = (const float*)d_in[4];
    const float* W_lv  = (const float*)d_in[5];
    const float* W_rv  = (const float*)d_in[6];
    const float* W_out = (const float*)d_in[7];

    float* ws = (float*)d_ws;
    float* lk = ws + 0 * (size_t)ROWS * EE;
    float* rk = ws + 1 * (size_t)ROWS * EE;
    float* lv = ws + 2 * (size_t)ROWS * EE;
    float* rv = ws + 3 * (size_t)ROWS * EE;

    proj_kernel<<<ROWS, 256, 0, stream>>>(query, key_t, value,
                                          W_lk, W_rk, W_lv, W_rv,
                                          lk, rk, lv, rv);
    attn_kernel<<<ROWS, 256, 0, stream>>>(lk, rk, lv, rv, W_out, (float*)d_out);
}

// Round 3
// 94.817 us; speedup vs baseline: 1.3092x; 1.3092x over previous
//
#include <hip/hip_runtime.h>

// B=2, N=24, E=128, H=8, D=16
#define BB 2
#define NN 24
#define EE 128
#define HH 8
#define DD 16
#define ROWS (BB * NN * NN)   // 1152

// ---------------------------------------------------------------------------
// K0: transpose the five 128x128 weight matrices into ws so later reads are
// coalesced (WT[k][j], lane = j). LDS 32x33 tile transpose, 80 blocks.
// wt layout: [0]=WlkT [1]=WrkT [2]=WlvT [3]=WrvT [4]=WoutT, each 16384 floats.
// ---------------------------------------------------------------------------
__global__ __launch_bounds__(256) void transpose_kernel(
    const float* __restrict__ W_lk, const float* __restrict__ W_rk,
    const float* __restrict__ W_lv, const float* __restrict__ W_rv,
    const float* __restrict__ W_out, float* __restrict__ wt)
{
    __shared__ float ld[32][33];
    const int blk  = blockIdx.x;
    const int mat  = blk / 16;
    const int tile = blk % 16;
    const int ti = tile >> 2, tj = tile & 3;
    const float* W;
    switch (mat) {
        case 0: W = W_lk; break; case 1: W = W_rk; break;
        case 2: W = W_lv; break; case 3: W = W_rv; break;
        default: W = W_out; break;
    }
    float* WT = wt + mat * 16384;
    const int t = threadIdx.x;
    #pragma unroll
    for (int e = t; e < 1024; e += 256) {
        const int r = e >> 5, c = e & 31;
        ld[r][c] = W[(ti * 32 + r) * EE + tj * 32 + c];   // coalesced read
    }
    __syncthreads();
    #pragma unroll
    for (int e = t; e < 1024; e += 256) {
        const int c = e >> 5, r = e & 31;
        WT[(tj * 32 + c) * EE + ti * 32 + r] = ld[r][c];  // coalesced write
    }
}

// ---------------------------------------------------------------------------
// K1: projections Y = X @ W^T via transposed weights (coalesced).
// Grid 576 = 4 mats x 144 tiles(8 rows). 256 thr: j = t&127, rowgroup = t>>7.
// No LDS, no syncthreads. X reads are wave-uniform (broadcast/scalar).
// ---------------------------------------------------------------------------
__global__ __launch_bounds__(256) void proj_kernel(
    const float* __restrict__ query, const float* __restrict__ key_t,
    const float* __restrict__ value, const float* __restrict__ wt,
    float* __restrict__ proj)
{
    const int blk  = blockIdx.x;
    const int mat  = blk / 144;
    const int tile = blk % 144;
    const int t  = threadIdx.x;
    const int j  = t & 127;
    const int rg = t >> 7;
    const float* X  = (mat == 0) ? query : (mat == 1) ? key_t : value;
    const float* WT = wt + mat * 16384;
    float* Y = proj + (size_t)mat * ROWS * EE;
    const int r0 = tile * 8 + rg * 4;
    const float* xbase = X + (size_t)r0 * EE;

    float acc[4] = {0.f, 0.f, 0.f, 0.f};
    #pragma unroll
    for (int kk = 0; kk < 32; ++kk) {
        float4 xv[4];
        #pragma unroll
        for (int rr = 0; rr < 4; ++rr)
            xv[rr] = *(const float4*)(xbase + rr * EE + kk * 4);
        const float w0 = WT[(kk * 4 + 0) * EE + j];
        const float w1 = WT[(kk * 4 + 1) * EE + j];
        const float w2 = WT[(kk * 4 + 2) * EE + j];
        const float w3 = WT[(kk * 4 + 3) * EE + j];
        #pragma unroll
        for (int rr = 0; rr < 4; ++rr) {
            acc[rr] += w0 * xv[rr].x;
            acc[rr] += w1 * xv[rr].y;
            acc[rr] += w2 * xv[rr].z;
            acc[rr] += w3 * xv[rr].w;
        }
    }
    #pragma unroll
    for (int rr = 0; rr < 4; ++rr)
        Y[(size_t)(r0 + rr) * EE + j] = acc[rr];
}

// ---------------------------------------------------------------------------
// K2: attention core + fused out-projection. ONE WAVE per (b,x,y).
// No LDS, no syncthreads; shuffles only.
//   A: s[a,h] = 0.25 * dot16(lk[b,x,a,h,:], rk[b,a,y,h,:]), 3 per lane
//      (index il = lane + 64p: a = il>>3, h = il&7)
//   B: softmax over a within head-group lanes {l : l&7 == h} (xor 8/16/32)
//   C: xloc[o], o = 2*lane+{0,1}: sum_a att[a,h] * lv[..o] * rv[..o]
//   D: out[j] = sum_i xloc[i] * WoutT[i][j], j = 2*lane+{0,1} (coalesced)
// ---------------------------------------------------------------------------
__global__ __launch_bounds__(64) void attn_kernel(
    const float* __restrict__ proj, const float* __restrict__ wt,
    float* __restrict__ out)
{
    const int lane = threadIdx.x;
    const int blk  = blockIdx.x;          // (b*24 + x)*24 + y
    const int y  = blk % NN;
    const int bx = blk / NN;              // b*24 + x
    const int b  = bx / NN;

    const float* lk = proj + 0 * (size_t)ROWS * EE;
    const float* rk = proj + 1 * (size_t)ROWS * EE;
    const float* lv = proj + 2 * (size_t)ROWS * EE;
    const float* rv = proj + 3 * (size_t)ROWS * EE;
    const float* WoutT = wt + 4 * 16384;

    // ---- A: scores ----
    float att[3];
    #pragma unroll
    for (int p = 0; p < 3; ++p) {
        const int il = lane + 64 * p;
        const int a  = il >> 3;
        const int h  = il & 7;
        const float4* lp = (const float4*)(lk + ((size_t)(bx * NN + a)) * EE + h * DD);
        const float4* rp = (const float4*)(rk + ((size_t)((b * NN + a) * NN + y)) * EE + h * DD);
        float acc = 0.f;
        #pragma unroll
        for (int c = 0; c < 4; ++c) {
            const float4 u = lp[c], v = rp[c];
            acc += u.x * v.x + u.y * v.y + u.z * v.z + u.w * v.w;
        }
        att[p] = acc * 0.25f;             // 1/sqrt(16)
    }

    // ---- B: softmax over a (per head) ----
    float m = fmaxf(att[0], fmaxf(att[1], att[2]));
    m = fmaxf(m, __shfl_xor(m, 8));
    m = fmaxf(m, __shfl_xor(m, 16));
    m = fmaxf(m, __shfl_xor(m, 32));
    float s = 0.f;
    #pragma unroll
    for (int p = 0; p < 3; ++p) { att[p] = __expf(att[p] - m); s += att[p]; }
    s += __shfl_xor(s, 8);
    s += __shfl_xor(s, 16);
    s += __shfl_xor(s, 32);
    const float inv = 1.f / s;
    #pragma unroll
    for (int p = 0; p < 3; ++p) att[p] *= inv;

    // ---- C: weighted outer-product reduction over a ----
    const int h = lane >> 3;              // = (2*lane)>>4
    float xx = 0.f, xy = 0.f;
    #pragma unroll
    for (int a = 0; a < NN; ++a) {
        const float attv = __shfl(att[a >> 3], ((a & 7) << 3) | h);
        const float2 l2 = *(const float2*)(lv + ((size_t)(bx * NN + a)) * EE + lane * 2);
        const float2 r2 = *(const float2*)(rv + ((size_t)((b * NN + a) * NN + y)) * EE + lane * 2);
        xx += attv * l2.x * r2.x;
        xy += attv * l2.y * r2.y;
    }

    // ---- D: fused out-projection ----
    float ox = 0.f, oy = 0.f;
    #pragma unroll
    for (int i = 0; i < EE; ++i) {
        const float xv = __shfl((i & 1) ? xy : xx, i >> 1);
        const float2 w2 = *(const float2*)(WoutT + i * EE + lane * 2);
        ox += xv * w2.x;
        oy += xv * w2.y;
    }
    *(float2*)(out + (size_t)blk * EE + lane * 2) = make_float2(ox, oy);
}

extern "C" void kernel_launch(void* const* d_in, const int* in_sizes, int n_in,
                              void* d_out, int out_size, void* d_ws, size_t ws_size,
                              hipStream_t stream) {
    const float* query = (const float*)d_in[0];
    const float* key_t = (const float*)d_in[1];
    const float* value = (const float*)d_in[2];
    const float* W_lk  = (const float*)d_in[3];
    const float* W_rk  = (const float*)d_in[4];
    const float* W_lv  = (const float*)d_in[5];
    const float* W_rv  = (const float*)d_in[6];
    const float* W_out = (const float*)d_in[7];

    float* wt   = (float*)d_ws;                 // 5 * 16384 floats
    float* proj = wt + 5 * 16384;               // 4 * 1152 * 128 floats

    transpose_kernel<<<80, 256, 0, stream>>>(W_lk, W_rk, W_lv, W_rv, W_out, wt);
    proj_kernel<<<576, 256, 0, stream>>>(query, key_t, value, wt, proj);
    attn_kernel<<<ROWS, 64, 0, stream>>>(proj, wt, (float*)d_out);
}